// Round 9
// baseline (402.741 us; speedup 1.0000x reference)
//
#include <hip/hip_runtime.h>
#include <hip/hip_bf16.h>

#define HW    16384   // 128*128
#define IMW   128
#define IMH   128
#define CIN   256
#define CR    64
#define G     16
#define GC    16

typedef __attribute__((ext_vector_type(8))) short short8;
typedef __attribute__((ext_vector_type(4))) float floatx4;

static __device__ __forceinline__ short f2bf(float f) {
  union { float f; unsigned u; } v; v.f = f;
  unsigned r = v.u + 0x7fffu + ((v.u >> 16) & 1u);   // RNE
  return (short)(r >> 16);
}
static __device__ __forceinline__ float bf2f(short s) {
  union { unsigned u; float f; } v; v.u = ((unsigned)(unsigned short)s) << 16;
  return v.f;
}

#define GLL16(g, l) __builtin_amdgcn_global_load_lds( \
    (const __attribute__((address_space(1))) void*)(g), \
    (__attribute__((address_space(3))) void*)(l), 16, 0, 0)

// ---------------------------------------------------------------------------
// K0 (round-0 verified): convert w1 (fp32 [64][256]) -> bf16. 64 blocks.
// ---------------------------------------------------------------------------
__global__ __launch_bounds__(256) void k_cvt_w1(const float* __restrict__ w1,
                                                short* __restrict__ w1b) {
  const int i = blockIdx.x * 256 + threadIdx.x;      // 16384 elements
  w1b[i] = f2bf(w1[i]);
}

// ---------------------------------------------------------------------------
// K1: 1x1 conv 256->64 as bf16 MFMA GEMM, x staged through LDS via
// global_load_lds width=16. NEW vs r6: K=64 per barrier-pair (4 GLL16 =
// 16 KB staged, 8 MFMA per stage, 4 loop iterations instead of 8) —
// halves the number of full vmcnt-drain barrier stalls per block.
// MFMA order unchanged (kk half then kk+32 half) -> bit-exact vs r6.
// Block 256 = 4 waves; wave = 16 px x 64 outputs. Grid 2048. LDS 16 KB.
// ---------------------------------------------------------------------------
__global__ __launch_bounds__(256) void k_conv1_mfma(const float* __restrict__ x,
                                                    const short* __restrict__ w1b,
                                                    const float* __restrict__ b1,
                                                    short* __restrict__ y1b) {
  __shared__ float xs[4096];            // [64 k][64 px] fp32, 16 KB
  const int blk  = blockIdx.x;          // b*256 + pixel-tile
  const int b    = blk >> 8;
  const int pt   = blk & 255;
  const int tid  = threadIdx.x;
  const int wave = tid >> 6;
  const int lane = tid & 63;
  const int quad = lane >> 4;
  const int l16  = lane & 15;
  const int px0  = pt * 64;
  const int p    = px0 + wave * 16 + l16;

  const float* xb = x + (size_t)b * CIN * HW + px0;
  const int krow = tid >> 4;            // 0..15
  const int scol = (tid & 15) * 4;      // 0..60

  floatx4 acc[4];
#pragma unroll
  for (int mt = 0; mt < 4; ++mt)
#pragma unroll
    for (int r = 0; r < 4; ++r) acc[mt][r] = b1[mt * 16 + quad * 4 + r];

#pragma unroll 1
  for (int kk = 0; kk < CIN; kk += 64) {
    GLL16(xb + (size_t)(kk +      krow) * HW + scol, xs        + wave * 256);
    GLL16(xb + (size_t)(kk + 16 + krow) * HW + scol, xs + 1024 + wave * 256);
    GLL16(xb + (size_t)(kk + 32 + krow) * HW + scol, xs + 2048 + wave * 256);
    GLL16(xb + (size_t)(kk + 48 + krow) * HW + scol, xs + 3072 + wave * 256);
    __syncthreads();   // drains vmcnt -> whole [64][64] tile visible

    short8 af0[4], af1[4];
#pragma unroll
    for (int mt = 0; mt < 4; ++mt) {
      af0[mt] = *(const short8*)(w1b + (mt * 16 + l16) * CIN + kk + quad * 8);
      af1[mt] = *(const short8*)(w1b + (mt * 16 + l16) * CIN + kk + 32 + quad * 8);
    }

    short8 bf0, bf1;
#pragma unroll
    for (int j = 0; j < 8; ++j)
      bf0[j] = f2bf(xs[(quad * 8 + j) * 64 + wave * 16 + l16]);
#pragma unroll
    for (int j = 0; j < 8; ++j)
      bf1[j] = f2bf(xs[2048 + (quad * 8 + j) * 64 + wave * 16 + l16]);

#pragma unroll
    for (int mt = 0; mt < 4; ++mt)
      acc[mt] = __builtin_amdgcn_mfma_f32_16x16x32_bf16(af0[mt], bf0, acc[mt], 0, 0, 0);
#pragma unroll
    for (int mt = 0; mt < 4; ++mt)
      acc[mt] = __builtin_amdgcn_mfma_f32_16x16x32_bf16(af1[mt], bf1, acc[mt], 0, 0, 0);
    __syncthreads();   // protect xs before next stage
  }

  short* yb = y1b + (size_t)b * CR * HW + p;
#pragma unroll
  for (int mt = 0; mt < 4; ++mt)
#pragma unroll
    for (int r = 0; r < 4; ++r)
      yb[(size_t)(mt * 16 + quad * 4 + r) * HW] = f2bf(acc[mt][r]);
}

// ---------------------------------------------------------------------------
// K2 (r1-verified, unchanged control): depthwise 3x3 over y1b (bf16),
// zero pad 1. Thread = 2 rows x 8 cols (short8). Grid 2048.
// ---------------------------------------------------------------------------
__global__ __launch_bounds__(256) void k_dw(const short* __restrict__ y1b,
                                            const float* __restrict__ wd,
                                            const float* __restrict__ bd,
                                            short* __restrict__ y2b) {
  const int blk   = blockIdx.x;         // ((b*64 + c)*4 + strip)
  const int strip = blk & 3;
  const int c     = (blk >> 2) & 63;
  const int b     = blk >> 8;
  const int tcol  = threadIdx.x & 15;
  const int trow  = threadIdx.x >> 4;
  const int r0    = strip * 32 + trow * 2;
  const int c0    = tcol * 8;

  const short* src = y1b + (size_t)(b * CR + c) * HW;

  const float mcl = c0 > 0 ? 1.f : 0.f;
  const float mcr = c0 + 8 < IMW ? 1.f : 0.f;
  const int   cl  = c0 > 0 ? c0 - 1 : 0;
  const int   crr = c0 + 8 < IMW ? c0 + 8 : IMW - 1;

  float f[4][10];
#pragma unroll
  for (int i = 0; i < 4; ++i) {
    const int rr = r0 - 1 + i;
    const int rc = rr < 0 ? 0 : (rr > IMH - 1 ? IMH - 1 : rr);
    const float mr = (rr < 0 || rr > IMH - 1) ? 0.f : 1.f;
    const short* row = src + rc * IMW;
    const short8 v = *(const short8*)(row + c0);
#pragma unroll
    for (int j = 0; j < 8; ++j) f[i][j + 1] = mr * bf2f(v[j]);
    f[i][0] = mr * mcl * bf2f(row[cl]);
    f[i][9] = mr * mcr * bf2f(row[crr]);
  }

  float wv[9];
#pragma unroll
  for (int j = 0; j < 9; ++j) wv[j] = wd[c * 9 + j];
  const float bias = bd[c];

  short* dst = y2b + (size_t)(b * CR + c) * HW + r0 * IMW + c0;
#pragma unroll
  for (int i = 0; i < 2; ++i) {
    short8 o;
#pragma unroll
    for (int xcol = 0; xcol < 8; ++xcol) {
      float acc = bias;
#pragma unroll
      for (int kh = 0; kh < 3; ++kh)
#pragma unroll
        for (int kw = 0; kw < 3; ++kw)
          acc += wv[kh * 3 + kw] * f[i + kh][xcol + kw];
      o[xcol] = f2bf(acc);
    }
    *(short8*)(dst + i * IMW) = o;
  }
}

// ---------------------------------------------------------------------------
// K3: fused conv2 + involution. NEW vs r8: 4 groups per block (grid 2048).
// Phase-1's 64 strided y2 loads/thread now feed 4 groups' weights (144 FMA
// per c-iter vs 72) — halves chip-wide latency-exposed load count; phase-2
// reuses the same 9 tap addresses for 64 channels. Per-output FMA
// expressions and order identical -> bit-exact vs r8.
// XCD swizzle kept, adjusted: wgid = (bid&7)*256 + (bid>>3) (2048%8==0,
// bijective; XCD k gets exactly batch k -> y2[b] L2-resident).
// 8x32 px tile. __launch_bounds__(256,4) caps VGPR at 128 for >=4 blk/CU.
// ---------------------------------------------------------------------------
__global__ __launch_bounds__(256, 4) void k_conv2invol(const float* __restrict__ x,
                                                       const short* __restrict__ y2b,
                                                       const float* __restrict__ w2,
                                                       const float* __restrict__ b2,
                                                       float* __restrict__ out) {
  const int bid  = blockIdx.x;
  const int blk  = (bid & 7) * 256 + (bid >> 3);   // XCD-aware bijection
  const int tile = blk & 63;           // 16 row-tiles x 4 col-tiles
  const int gp   = (blk >> 6) & 3;     // 4 group-pairs of 4
  const int b    = blk >> 8;
  const int g0   = gp * 4;
  const int tid  = threadIdx.x;
  const int tr   = tid >> 5;           // 0..7
  const int tc   = tid & 31;           // 0..31
  const int h    = (tile >> 2) * 8 + tr;
  const int w    = (tile & 3) * 32 + tc;
  const int p    = h * IMW + w;

  // ---- phase 1: dynamic weights for this pixel, groups g0..g0+3 ----
  float wv[4][9];
#pragma unroll
  for (int q = 0; q < 4; ++q)
#pragma unroll
    for (int j = 0; j < 9; ++j) wv[q][j] = b2[(g0 + q) * 9 + j];

  const short* y2p = y2b + (size_t)b * CR * HW + p;
#pragma unroll 2
  for (int c = 0; c < CR; c += 4) {
    const float v0 = bf2f(y2p[(size_t)(c + 0) * HW]);
    const float v1 = bf2f(y2p[(size_t)(c + 1) * HW]);
    const float v2 = bf2f(y2p[(size_t)(c + 2) * HW]);
    const float v3 = bf2f(y2p[(size_t)(c + 3) * HW]);
#pragma unroll
    for (int q = 0; q < 4; ++q)
#pragma unroll
      for (int j = 0; j < 9; ++j) {
        const float4 wq = *(const float4*)(w2 + ((g0 + q) * 9 + j) * CR + c); // uniform
        wv[q][j] += wq.x * v0 + wq.y * v1 + wq.z * v2 + wq.w * v3;
      }
  }

  // ---- fold borders into weights; clamped tap offsets ----
  const int   hcl[3] = {h > 0 ? h - 1 : 0, h, h < IMH - 1 ? h + 1 : IMH - 1};
  const int   wcl[3] = {w > 0 ? w - 1 : 0, w, w < IMW - 1 ? w + 1 : IMW - 1};
  const float mrow[3] = {h > 0 ? 1.f : 0.f, 1.f, h < IMH - 1 ? 1.f : 0.f};
  const float mcol[3] = {w > 0 ? 1.f : 0.f, 1.f, w < IMW - 1 ? 1.f : 0.f};
  int rel[9];
#pragma unroll
  for (int kh = 0; kh < 3; ++kh)
#pragma unroll
    for (int kw = 0; kw < 3; ++kw) {
      rel[kh * 3 + kw] = hcl[kh] * IMW + wcl[kw];
      const float m = mrow[kh] * mcol[kw];
#pragma unroll
      for (int q = 0; q < 4; ++q) wv[q][kh * 3 + kw] *= m;
    }

  // ---- phase 2: involution, branchless taps through L1 ----
  const float* xb = x + (size_t)b * CIN * HW;
  float*       ob = out + (size_t)b * CIN * HW;

#pragma unroll
  for (int q = 0; q < 4; ++q) {
#pragma unroll 4
    for (int cc = 0; cc < GC; ++cc) {
      const int ch = (g0 + q) * GC + cc;
      const float* xp = xb + (size_t)ch * HW;
      float acc = 0.f;
#pragma unroll
      for (int j = 0; j < 9; ++j) acc += wv[q][j] * xp[rel[j]];
      ob[(size_t)ch * HW + p] = acc;
    }
  }
}

extern "C" void kernel_launch(void* const* d_in, const int* in_sizes, int n_in,
                              void* d_out, int out_size, void* d_ws, size_t ws_size,
                              hipStream_t stream) {
  const float* x  = (const float*)d_in[0];
  const float* w1 = (const float*)d_in[1];
  const float* b1 = (const float*)d_in[2];
  const float* wd = (const float*)d_in[3];
  const float* bd = (const float*)d_in[4];
  const float* w2 = (const float*)d_in[5];
  const float* b2 = (const float*)d_in[6];
  float* out = (float*)d_out;

  // ws layout (33.62 MB, r6/r8-verified):
  //   w1b bf16 (32 KB, padded to 64 KB) | y1b bf16 16.78 MB | y2b bf16 16.78 MB
  short* w1b = (short*)d_ws;
  short* y1b = (short*)((char*)d_ws + 65536);
  short* y2b = y1b + (size_t)8 * CR * HW;

  k_cvt_w1<<<dim3(64), dim3(256), 0, stream>>>(w1, w1b);
  k_conv1_mfma<<<dim3(2048), dim3(256), 0, stream>>>(x, w1b, b1, y1b);
  k_dw<<<dim3(2048), dim3(256), 0, stream>>>(y1b, wd, bd, y2b);
  k_conv2invol<<<dim3(2048), dim3(256), 0, stream>>>(x, y2b, w2, b2, out);
}

// Round 10
// 350.650 us; speedup vs baseline: 1.1486x; 1.1486x over previous
//
#include <hip/hip_runtime.h>
#include <hip/hip_bf16.h>

#define HW    16384   // 128*128
#define IMW   128
#define IMH   128
#define CIN   256
#define CR    64
#define G     16
#define GC    16

typedef __attribute__((ext_vector_type(8))) short short8;
typedef __attribute__((ext_vector_type(4))) float floatx4;

static __device__ __forceinline__ short f2bf(float f) {
  union { float f; unsigned u; } v; v.f = f;
  unsigned r = v.u + 0x7fffu + ((v.u >> 16) & 1u);   // RNE
  return (short)(r >> 16);
}
static __device__ __forceinline__ float bf2f(short s) {
  union { unsigned u; float f; } v; v.u = ((unsigned)(unsigned short)s) << 16;
  return v.f;
}

#define GLL16(g, l) __builtin_amdgcn_global_load_lds( \
    (const __attribute__((address_space(1))) void*)(g), \
    (__attribute__((address_space(3))) void*)(l), 16, 0, 0)

// ---------------------------------------------------------------------------
// K0 (round-0 verified): convert w1 (fp32 [64][256]) -> bf16. 64 blocks.
// ---------------------------------------------------------------------------
__global__ __launch_bounds__(256) void k_cvt_w1(const float* __restrict__ w1,
                                                short* __restrict__ w1b) {
  const int i = blockIdx.x * 256 + threadIdx.x;      // 16384 elements
  w1b[i] = f2bf(w1[i]);
}

// ---------------------------------------------------------------------------
// K1: 1x1 conv 256->64 as bf16 MFMA GEMM, NEW: 2-phase double-buffered
// pipeline (T3 minimum). Old form did GLL -> __syncthreads() (full
// vmcnt(0) drain) -> compute, 4-8 times per block: every K-tile paid the
// whole ~900cy HBM latency serially. Now: stage tile t+1 into buf[(t+1)&1],
// counted s_waitcnt vmcnt(2) (tile t complete, t+1's 2 loads STAY IN
// FLIGHT across the barrier), raw s_barrier, compute tile t, raw
// s_barrier. No full drain inside the loop. 8 tiles of K=32.
// MFMA order identical (kk ascending, mt 0..3) -> bit-exact vs r6/r8.
// Block 256 = 4 waves; wave = 16 px x 64 outputs. Grid 2048. LDS 16 KB.
// ---------------------------------------------------------------------------
__global__ __launch_bounds__(256) void k_conv1_mfma(const float* __restrict__ x,
                                                    const short* __restrict__ w1b,
                                                    const float* __restrict__ b1,
                                                    short* __restrict__ y1b) {
  __shared__ float xs[2][2048];         // two [32 k][64 px] fp32 tiles
  const int blk  = blockIdx.x;          // b*256 + pixel-tile
  const int b    = blk >> 8;
  const int pt   = blk & 255;
  const int tid  = threadIdx.x;
  const int wave = tid >> 6;
  const int lane = tid & 63;
  const int quad = lane >> 4;
  const int l16  = lane & 15;
  const int px0  = pt * 64;
  const int p    = px0 + wave * 16 + l16;

  const float* xb = x + (size_t)b * CIN * HW + px0;
  const int krow = tid >> 4;            // 0..15
  const int scol = (tid & 15) * 4;      // 0..60
  const int wo   = wave * 256;          // wave's 4-krow slice in a tile half

  floatx4 acc[4];
#pragma unroll
  for (int mt = 0; mt < 4; ++mt)
#pragma unroll
    for (int r = 0; r < 4; ++r) acc[mt][r] = b1[mt * 16 + quad * 4 + r];

  // ---- prologue: stage tile 0 (k 0..31) ----
  GLL16(xb + (size_t)(krow) * HW + scol,      &xs[0][0]    + wo);
  GLL16(xb + (size_t)(16 + krow) * HW + scol, &xs[0][1024] + wo);

#pragma unroll 1
  for (int t = 0; t < 8; ++t) {
    const int kk = t * 32;
    // ---- issue next stage BEFORE waiting (loads overlap compute) ----
    if (t < 7) {
      GLL16(xb + (size_t)(kk + 32 + krow) * HW + scol, &xs[(t + 1) & 1][0]    + wo);
      GLL16(xb + (size_t)(kk + 48 + krow) * HW + scol, &xs[(t + 1) & 1][1024] + wo);
      asm volatile("s_waitcnt vmcnt(2)" ::: "memory");  // tile t done; t+1 in flight
    } else {
      asm volatile("s_waitcnt vmcnt(0)" ::: "memory");  // epilogue drain
    }
    __builtin_amdgcn_s_barrier();       // tile t visible to all waves
    asm volatile("" ::: "memory");

    const float* cur = &xs[t & 1][0];
    short8 af[4];
#pragma unroll
    for (int mt = 0; mt < 4; ++mt)
      af[mt] = *(const short8*)(w1b + (mt * 16 + l16) * CIN + kk + quad * 8);

    short8 bfrag;
#pragma unroll
    for (int j = 0; j < 8; ++j)
      bfrag[j] = f2bf(cur[(quad * 8 + j) * 64 + wave * 16 + l16]);

#pragma unroll
    for (int mt = 0; mt < 4; ++mt)
      acc[mt] = __builtin_amdgcn_mfma_f32_16x16x32_bf16(af[mt], bfrag, acc[mt], 0, 0, 0);

    asm volatile("" ::: "memory");
    __builtin_amdgcn_s_barrier();       // all waves done reading tile t
                                        // (safe to overwrite buf[t&1] at t+1)
  }

  short* yb = y1b + (size_t)b * CR * HW + p;
#pragma unroll
  for (int mt = 0; mt < 4; ++mt)
#pragma unroll
    for (int r = 0; r < 4; ++r)
      yb[(size_t)(mt * 16 + quad * 4 + r) * HW] = f2bf(acc[mt][r]);
}

// ---------------------------------------------------------------------------
// K2 (r1-verified, unchanged control): depthwise 3x3 over y1b (bf16),
// zero pad 1. Thread = 2 rows x 8 cols (short8). Grid 2048.
// ---------------------------------------------------------------------------
__global__ __launch_bounds__(256) void k_dw(const short* __restrict__ y1b,
                                            const float* __restrict__ wd,
                                            const float* __restrict__ bd,
                                            short* __restrict__ y2b) {
  const int blk   = blockIdx.x;         // ((b*64 + c)*4 + strip)
  const int strip = blk & 3;
  const int c     = (blk >> 2) & 63;
  const int b     = blk >> 8;
  const int tcol  = threadIdx.x & 15;
  const int trow  = threadIdx.x >> 4;
  const int r0    = strip * 32 + trow * 2;
  const int c0    = tcol * 8;

  const short* src = y1b + (size_t)(b * CR + c) * HW;

  const float mcl = c0 > 0 ? 1.f : 0.f;
  const float mcr = c0 + 8 < IMW ? 1.f : 0.f;
  const int   cl  = c0 > 0 ? c0 - 1 : 0;
  const int   crr = c0 + 8 < IMW ? c0 + 8 : IMW - 1;

  float f[4][10];
#pragma unroll
  for (int i = 0; i < 4; ++i) {
    const int rr = r0 - 1 + i;
    const int rc = rr < 0 ? 0 : (rr > IMH - 1 ? IMH - 1 : rr);
    const float mr = (rr < 0 || rr > IMH - 1) ? 0.f : 1.f;
    const short* row = src + rc * IMW;
    const short8 v = *(const short8*)(row + c0);
#pragma unroll
    for (int j = 0; j < 8; ++j) f[i][j + 1] = mr * bf2f(v[j]);
    f[i][0] = mr * mcl * bf2f(row[cl]);
    f[i][9] = mr * mcr * bf2f(row[crr]);
  }

  float wv[9];
#pragma unroll
  for (int j = 0; j < 9; ++j) wv[j] = wd[c * 9 + j];
  const float bias = bd[c];

  short* dst = y2b + (size_t)(b * CR + c) * HW + r0 * IMW + c0;
#pragma unroll
  for (int i = 0; i < 2; ++i) {
    short8 o;
#pragma unroll
    for (int xcol = 0; xcol < 8; ++xcol) {
      float acc = bias;
#pragma unroll
      for (int kh = 0; kh < 3; ++kh)
#pragma unroll
        for (int kw = 0; kw < 3; ++kw)
          acc += wv[kh * 3 + kw] * f[i + kh][xcol + kw];
      o[xcol] = f2bf(acc);
    }
    *(short8*)(dst + i * IMW) = o;
  }
}

// ---------------------------------------------------------------------------
// K3 (r8-verified EXACT — best k3 across 7 variants; 4-group r9 refuted):
// fused conv2 + involution, 8x32 px tile, 2 groups/block, phase-1 unroll 2,
// XCD swizzle (FETCH 223->98 MB). Grid 4096.
// ---------------------------------------------------------------------------
__global__ __launch_bounds__(256) void k_conv2invol(const float* __restrict__ x,
                                                    const short* __restrict__ y2b,
                                                    const float* __restrict__ w2,
                                                    const float* __restrict__ b2,
                                                    float* __restrict__ out) {
  const int bid  = blockIdx.x;
  const int blk  = (bid & 7) * 512 + (bid >> 3);   // XCD-aware bijection
  const int tile = blk & 63;           // 16 row-tiles x 4 col-tiles
  const int gp   = (blk >> 6) & 7;
  const int b    = blk >> 9;
  const int g0   = gp * 2;
  const int tid  = threadIdx.x;
  const int tr   = tid >> 5;           // 0..7
  const int tc   = tid & 31;           // 0..31
  const int h    = (tile >> 2) * 8 + tr;
  const int w    = (tile & 3) * 32 + tc;
  const int p    = h * IMW + w;

  // ---- phase 1: dynamic weights for this pixel, groups g0, g0+1 ----
  float wv[2][9];
#pragma unroll
  for (int q = 0; q < 2; ++q)
#pragma unroll
    for (int j = 0; j < 9; ++j) wv[q][j] = b2[(g0 + q) * 9 + j];

  const short* y2p = y2b + (size_t)b * CR * HW + p;
#pragma unroll 2
  for (int c = 0; c < CR; c += 4) {
    const float v0 = bf2f(y2p[(size_t)(c + 0) * HW]);
    const float v1 = bf2f(y2p[(size_t)(c + 1) * HW]);
    const float v2 = bf2f(y2p[(size_t)(c + 2) * HW]);
    const float v3 = bf2f(y2p[(size_t)(c + 3) * HW]);
#pragma unroll
    for (int q = 0; q < 2; ++q)
#pragma unroll
      for (int j = 0; j < 9; ++j) {
        const float4 wq = *(const float4*)(w2 + ((g0 + q) * 9 + j) * CR + c); // uniform
        wv[q][j] += wq.x * v0 + wq.y * v1 + wq.z * v2 + wq.w * v3;
      }
  }

  // ---- fold borders into weights; clamped tap offsets ----
  const int   hcl[3] = {h > 0 ? h - 1 : 0, h, h < IMH - 1 ? h + 1 : IMH - 1};
  const int   wcl[3] = {w > 0 ? w - 1 : 0, w, w < IMW - 1 ? w + 1 : IMW - 1};
  const float mr[3]  = {h > 0 ? 1.f : 0.f, 1.f, h < IMH - 1 ? 1.f : 0.f};
  const float mc[3]  = {w > 0 ? 1.f : 0.f, 1.f, w < IMW - 1 ? 1.f : 0.f};
  int rel[9];
#pragma unroll
  for (int kh = 0; kh < 3; ++kh)
#pragma unroll
    for (int kw = 0; kw < 3; ++kw) {
      rel[kh * 3 + kw] = hcl[kh] * IMW + wcl[kw];
      const float m = mr[kh] * mc[kw];
      wv[0][kh * 3 + kw] *= m;
      wv[1][kh * 3 + kw] *= m;
    }

  // ---- phase 2: involution, branchless taps through L1 ----
  const float* xb = x + (size_t)b * CIN * HW;
  float*       ob = out + (size_t)b * CIN * HW;

#pragma unroll
  for (int q = 0; q < 2; ++q) {
#pragma unroll 4
    for (int cc = 0; cc < GC; ++cc) {
      const int ch = (g0 + q) * GC + cc;
      const float* xp = xb + (size_t)ch * HW;
      float acc = 0.f;
#pragma unroll
      for (int j = 0; j < 9; ++j) acc += wv[q][j] * xp[rel[j]];
      ob[(size_t)ch * HW + p] = acc;
    }
  }
}

extern "C" void kernel_launch(void* const* d_in, const int* in_sizes, int n_in,
                              void* d_out, int out_size, void* d_ws, size_t ws_size,
                              hipStream_t stream) {
  const float* x  = (const float*)d_in[0];
  const float* w1 = (const float*)d_in[1];
  const float* b1 = (const float*)d_in[2];
  const float* wd = (const float*)d_in[3];
  const float* bd = (const float*)d_in[4];
  const float* w2 = (const float*)d_in[5];
  const float* b2 = (const float*)d_in[6];
  float* out = (float*)d_out;

  // ws layout (33.62 MB, r6/r8-verified):
  //   w1b bf16 (32 KB, padded to 64 KB) | y1b bf16 16.78 MB | y2b bf16 16.78 MB
  short* w1b = (short*)d_ws;
  short* y1b = (short*)((char*)d_ws + 65536);
  short* y2b = y1b + (size_t)8 * CR * HW;

  k_cvt_w1<<<dim3(64), dim3(256), 0, stream>>>(w1, w1b);
  k_conv1_mfma<<<dim3(2048), dim3(256), 0, stream>>>(x, w1b, b1, y1b);
  k_dw<<<dim3(2048), dim3(256), 0, stream>>>(y1b, wd, bd, y2b);
  k_conv2invol<<<dim3(4096), dim3(256), 0, stream>>>(x, y2b, w2, b2, out);
}